// Round 11
// baseline (381.144 us; speedup 1.0000x reference)
//
#include <hip/hip_runtime.h>
#include <math.h>

#ifndef M_PI
#define M_PI 3.14159265358979323846
#endif

// ---- problem constants ----
#define BB 4
#define TT 4
#define NSEM 16
#define CHL 22            // NC + NUM_SEM
#define CHMF 28           // NC + NC + NUM_SEM
#define ML 240
#define MG 960
#define VR 100
#define HS 120            // FRAME_H/DU
#define WSW 160           // FRAME_W/DU
#define NPL 18            // plane channels: 0=occ,1=exp,2..17=sem
#define CPAD 24           // padded floats per cell (96 B, float4-aligned)
#define MLSQ (ML*ML)      // 57600
#define MGSQ (MG*MG)      // 921600
#define VRSQ (VR*VR)      // 10000
#define PPT (HS*WSW)      // 19200 points per (b,t)
#define NPART 12          // row-bands for LDS splat
#define PR 9              // rows per band (12*9=108 >= 100)
#define NGRP 5            // splat channel groups
#define NSPLAT (BB*TT*NPART*NGRP)   // 960 splat blocks
#define NUPDL (4*60*BB*7)           // 6720 updl blocks

// ---- output layout (floats) ----
#define SZ_MF (BB*TT*CHMF*MLSQ)
#define SZ_FL (BB*CHL*MLSQ)
#define SZ_FG (BB*CHL*MGSQ)
#define OFF_FL SZ_MF
#define OFF_FG (OFF_FL + SZ_FL)
#define OFF_LP (OFF_FG + SZ_FG)
#define OFF_GP (OFF_LP + BB*TT*3)
#define OFF_LMB (OFF_GP + BB*TT*3)
#define OFF_ORG (OFF_LMB + BB*TT*4)

// ---- ws layout (floats) ----
#define WS_SCAL 0                                   // (b*TT+t)*8: c,s,stx,sty,acx,acy
#define WS_FLAGS (WS_SCAL + BB*TT*8)                // b*4: anyDone, zeroWin, lastUpd
#define WS_CACHE (WS_FLAGS + 4*BB)                  // B*6*240*240 init gmax cache
#define WS_PLANES (WS_CACHE + BB*6*MLSQ)            // B*T*10000*24 channel-innermost
#define WS_I2 (WS_PLANES + BB*TT*VRSQ*CPAD)         // B*T*18*240*240
#define PTSN (BB*TT*PPT)
#define WS_GY (WS_I2 + BB*TT*NPL*MLSQ)
#define WS_GX (WS_GY + PTSN)
#define WS_WZA (WS_GX + PTSN)
#define WS_WZL (WS_WZA + PTSN)
#define WS_SEMDS (WS_WZL + PTSN)                    // B*T*16*PPT

// fg init for one (b, c, 4x4-cell idx): copy/zero + (c<6) cache + out-window gmax.
// Flags computed locally from dones/updg -> no dependency on poseall.
__device__ __forceinline__ void fginit_block(const float* __restrict__ igm,
                                             const int* __restrict__ dones,
                                             const int* __restrict__ updg,
                                             const int* __restrict__ lmb,
                                             float* __restrict__ fg,
                                             float* __restrict__ out,
                                             float* __restrict__ ws,
                                             int b, int c, int idx)
{
    int i = idx / ML, j = idx % ML;
    int lastDone = -1, lastUpd = -1;
    #pragma unroll
    for (int t = 0; t < TT; t++) {
        if (dones[b*TT+t]) lastDone = t;
        if (updg[b*TT+t])  lastUpd  = t;
    }
    bool anyDone = lastDone >= 0;
    bool zeroWin = lastUpd < lastDone;
    int y0 = lmb[b*4+0], x0 = lmb[b*4+2];
    int iy0 = y0 >> 2, ix0 = x0 >> 2;
    bool inWin = (i >= iy0) && (i < iy0 + ML/4) && (j >= ix0) && (j < ix0 + ML/4);

    size_t base = ((size_t)b*CHL + c)*MGSQ + (size_t)(4*i)*MG + 4*j;
    const float* g = igm + base;
    float* go = fg + base;

    int act;                                         // 0=copy 1=zeros 2=skip(updl writes)
    if (inWin) act = zeroWin ? 1 : ((lastUpd >= 0) ? 2 : (anyDone ? 1 : 0));
    else       act = anyDone ? 1 : 0;

    if (c < 6) {
        float m = -3.0e38f;
        #pragma unroll
        for (int r = 0; r < 4; r++) {
            float4 q = *(const float4*)(g + (size_t)r*MG);
            if (act == 0) *(float4*)(go + (size_t)r*MG) = q;
            else if (act == 1) *(float4*)(go + (size_t)r*MG) = make_float4(0,0,0,0);
            m = fmaxf(m, fmaxf(fmaxf(q.x, q.y), fmaxf(q.z, q.w)));
        }
        ws[WS_CACHE + ((size_t)b*6 + c)*MLSQ + idx] = m;
        if (!inWin) {
            float v = m;
            for (int t = 0; t < TT; t++) {
                if (dones[b*TT+t]) v = 0.0f;
                out[(size_t)(b*TT+t)*CHMF*MLSQ + (6+c)*MLSQ + idx] = v;
            }
        }
    } else {
        if (act == 2) return;
        if (act == 1) {
            float4 z = make_float4(0,0,0,0);
            #pragma unroll
            for (int r = 0; r < 4; r++) *(float4*)(go + (size_t)r*MG) = z;
        } else {
            #pragma unroll
            for (int r = 0; r < 4; r++)
                *(float4*)(go + (size_t)r*MG) = *(const float4*)(g + (size_t)r*MG);
        }
    }
}

// ---- node 1: {poseall} ∥ {prep} ∥ {fginit ch0..5} ----
__global__ __launch_bounds__(256) void k_node1(const float* __restrict__ obs,
                                               const float* __restrict__ cam,
                                               const float* __restrict__ pd,
                                               const float* __restrict__ ilp,
                                               const float* __restrict__ org,
                                               const int* __restrict__ lmb,
                                               const int* __restrict__ dones,
                                               const int* __restrict__ updg,
                                               const float* __restrict__ igm,
                                               float* __restrict__ fg,
                                               float* __restrict__ out,
                                               float* __restrict__ ws)
{
    if (blockIdx.x == 0) {
        // ---- poseall ----
        int i = threadIdx.x;
        if (i < BB*TT) {
            int b = i / TT, t = i % TT;
            for (int k = 0; k < 4; k++) out[OFF_LMB + (b*TT+t)*4 + k] = (float)lmb[b*4+k];
            for (int k = 0; k < 3; k++) out[OFF_ORG + (b*TT+t)*3 + k] = org[b*3+k];
        }
        if (i >= BB) return;
        int b = i;
        float p0 = ilp[b*3+0], p1 = ilp[b*3+1], p2 = ilp[b*3+2];
        const float D2R = 0.017453292519943295f;
        int lastDone = -1, lastUpd = -1;
        for (int t = 0; t < TT; t++) {
            if (dones[b*TT+t]) { p0 = 6.0f; p1 = 6.0f; p2 = 0.0f; lastDone = t; }
            if (updg[b*TT+t]) lastUpd = t;
            float tr = p2 * D2R;
            float c0 = cosf(tr), s0 = sinf(tr);
            float q0 = pd[(b*TT+t)*3+0], q1 = pd[(b*TT+t)*3+1], q2 = pd[(b*TT+t)*3+2];
            float nx = p0 + q0*c0 - q1*s0;
            float ny = p1 + q0*s0 + q1*c0;
            float a  = p2 + q2*57.29577951308232f + 180.0f;
            float m  = fmodf(a, 360.0f); if (m < 0.0f) m += 360.0f;
            float nt = m - 180.0f;
            p0 = nx; p1 = ny; p2 = nt;
            out[OFF_LP + (b*TT+t)*3+0] = nx;
            out[OFF_LP + (b*TT+t)*3+1] = ny;
            out[OFF_LP + (b*TT+t)*3+2] = nt;
            out[OFF_GP + (b*TT+t)*3+0] = nx + org[b*3+0];
            out[OFF_GP + (b*TT+t)*3+1] = ny + org[b*3+1];
            out[OFF_GP + (b*TT+t)*3+2] = nt + org[b*3+2];
            float th = (90.0f - nt) * D2R;
            float ax = nx*100.0f/5.0f, ay = ny*100.0f/5.0f;
            float* sc = ws + WS_SCAL + (b*TT+t)*8;
            sc[0] = cosf(th);
            sc[1] = sinf(th);
            sc[2] = -(ax - 120.0f)/120.0f;
            sc[3] = -(ay - 120.0f)/120.0f;
            sc[4] = ax;
            sc[5] = ay;
        }
        ws[WS_FLAGS + b*4 + 0] = (lastDone >= 0) ? 1.0f : 0.0f;
        ws[WS_FLAGS + b*4 + 1] = (lastUpd < lastDone) ? 1.0f : 0.0f;
        ws[WS_FLAGS + b*4 + 2] = (float)lastUpd;
        return;
    }
    if (blockIdx.x <= 75*BB*TT) {
        // ---- prep ----
        int bb = blockIdx.x - 1;
        int bt = bb / 75;
        int b = bt / TT;
        int p = (bb % 75)*256 + threadIdx.x;         // < 19200
        int h = p / WSW, w = p % WSW;
        size_t pi = (size_t)bt*PPT + p;
        const float* ob = obs + (size_t)bt * 20 * 480 * 640;
        float d = ob[(size_t)(3*480 + 4*h)*640 + 4*w];
        if (!(d >= 50.0f && d <= 350.0f)) { ws[WS_GY + pi] = -1000.0f; return; }

        double fd = 640.0 / (2.0 * tan((79.0 * M_PI / 180.0) * 0.5));
        float ff  = (float)fd;
        float xsv = (float)(4*w - 320) / ff;
        float zrv = (240.0f - (float)(4*h)) / ff;
        float elev = atan2f(cam[b*16+9], cam[b*16+10]);
        float ce = cosf(elev), se = sinf(elev);
        float up  = d * zrv;
        float fwd = d*ce + up*se;
        float hgt = -d*se + up*ce + 88.0f;
        float gx = (d*xsv)/5.0f + 50.0f;
        float gy = fwd/5.0f;
        float gz = hgt/5.0f + 8.0f;                  // - ZMIN

        float z0 = floorf(gz);
        float wza = 0.0f, wzl = 0.0f;
        #pragma unroll
        for (int dz = 0; dz < 2; dz++) {
            float zi = z0 + dz;
            float wz = 1.0f - fabsf(gz - zi);
            if (zi >= 0.0f && zi < 80.0f) {
                wzl += wz;
                if (zi >= 13.0f && zi < 25.0f) wza += wz;
            }
        }
        if (wzl == 0.0f && wza == 0.0f) { ws[WS_GY + pi] = -1000.0f; return; }

        ws[WS_GY + pi]  = gy;
        ws[WS_GX + pi]  = gx;
        ws[WS_WZA + pi] = wza;
        ws[WS_WZL + pi] = wzl;

        if (wza > 0.0f) {
            const float* sb = ob + (size_t)4*480*640 + (size_t)(4*h)*640 + 4*w;
            float* so = ws + WS_SEMDS + (size_t)bt*NSEM*PPT + p;
            #pragma unroll
            for (int k = 0; k < NSEM; k++) {
                float s = 0.0f;
                #pragma unroll
                for (int r = 0; r < 4; r++) {
                    const float4 v = *(const float4*)(sb + (size_t)k*480*640 + r*640);
                    s += v.x + v.y + v.z + v.w;
                }
                so[(size_t)k*PPT] = s * 0.0625f;
            }
        }
        return;
    }
    // ---- fginit ch0..5 ----
    int fb = blockIdx.x - (1 + 75*BB*TT);
    int idx = (fb % 225)*256 + threadIdx.x;
    int c = (fb / 225) % 6;
    int b = fb / (225*6);
    fginit_block(igm, dones, updg, lmb, fg, out, ws, b, c, idx);
}

// ---- node 2: LDS-accumulated bilinear splat (alone) ----
__global__ __launch_bounds__(256) void k_splat2(const float* __restrict__ ws,
                                                float* __restrict__ planes)
{
    __shared__ float acc[4*PR*VR];                   // 14.4 KB
    int bid = blockIdx.x;
    // bid = (grp*NPART + part)*16 + bt
    int bt = bid & 15;
    int part = (bid >> 4) % NPART;
    int grp = bid / (16*NPART);
    int rlo = part * PR;
    int c0  = (grp == 0) ? 0 : (2 + 4*(grp-1));
    int nch = (grp == 0) ? 2 : 4;
    for (int e = threadIdx.x; e < nch*PR*VR; e += 256) acc[e] = 0.0f;
    __syncthreads();

    const float* gyA  = ws + WS_GY  + (size_t)bt*PPT;
    const float* gxA  = ws + WS_GX  + (size_t)bt*PPT;
    const float* wzaA = ws + WS_WZA + (size_t)bt*PPT;
    const float* wzlA = ws + WS_WZL + (size_t)bt*PPT;
    const float* semA = ws + WS_SEMDS + (size_t)bt*NSEM*PPT + (size_t)(c0-2)*PPT;

    for (int p = threadIdx.x; p < PPT; p += 256) {
        float gy = gyA[p];
        float y0 = floorf(gy);
        if (y0 > (float)(rlo + PR - 1) || y0 + 1.0f < (float)rlo) continue;
        float wza = wzaA[p];
        if (grp != 0 && wza <= 0.0f) continue;
        float gx  = gxA[p];
        float x0 = floorf(gx);
        float sem[4];
        if (grp != 0) {
            #pragma unroll
            for (int k = 0; k < 4; k++) sem[k] = semA[(size_t)k*PPT + p];
        }
        float wzl = (grp == 0) ? wzlA[p] : 0.0f;
        #pragma unroll
        for (int dy = 0; dy < 2; dy++) {
            float yi = y0 + dy;
            if (!(yi >= 0.0f && yi < 100.0f)) continue;
            int r = (int)yi - rlo;
            if (r < 0 || r >= PR) continue;
            float wy = 1.0f - fabsf(gy - yi);
            #pragma unroll
            for (int dx = 0; dx < 2; dx++) {
                float xi = x0 + dx;
                if (!(xi >= 0.0f && xi < 100.0f)) continue;
                float wxy = (1.0f - fabsf(gx - xi)) * wy;
                if (wxy <= 0.0f) continue;
                int cell = r*VR + (int)xi;
                if (grp == 0) {
                    if (wza > 0.0f) atomicAdd(&acc[cell], wza*wxy);
                    if (wzl > 0.0f) atomicAdd(&acc[PR*VR + cell], wzl*wxy);
                } else {
                    #pragma unroll
                    for (int k = 0; k < 4; k++) {
                        float sv = sem[k];
                        if (sv != 0.0f) atomicAdd(&acc[k*PR*VR + cell], sv*wza*wxy);
                    }
                }
            }
        }
    }
    __syncthreads();

    int nrows = 100 - rlo; if (nrows > PR) nrows = PR;
    if (nrows <= 0) return;
    float* pl = planes + (size_t)bt*VRSQ*CPAD;
    for (int e = threadIdx.x; e < nch*nrows*VR; e += 256) {
        int c = e / (nrows*VR);
        int rc = e % (nrows*VR);
        int r = rc / VR, x = rc % VR;
        pl[(size_t)((rlo + r)*VR + x)*CPAD + (c0 + c)] = acc[c*PR*VR + r*VR + x];
    }
}

// ---- node 3: fused gs2∘gs1, 18 channels, channel-innermost gather (alone) ----
__global__ __launch_bounds__(256) void k_gs(const float* __restrict__ planes,
                                            const float* __restrict__ ws,
                                            float* __restrict__ I2)
{
    int bt = blockIdx.x / 225;
    int idx = (blockIdx.x % 225)*256 + threadIdx.x;
    int i = idx / ML, j = idx % ML;
    const float* sc = ws + WS_SCAL + bt*8;
    float c = sc[0], s = sc[1], stx = sc[2], sty = sc[3];
    float* o = I2 + (size_t)bt*NPL*MLSQ + idx;
    const float* pl = planes + (size_t)bt*VRSQ*CPAD;

    int   soff[16];
    float sw[16];
    float wsum = 0.0f;
    {
        float xg = (float)j * (float)(2.0/239.0) - 1.0f + stx;
        float yg = (float)i * (float)(2.0/239.0) - 1.0f + sty;
        float x = (xg + 1.0f)*0.5f*239.0f;
        float y = (yg + 1.0f)*0.5f*239.0f;
        float x0 = floorf(x), y0 = floorf(y);
        #pragma unroll
        for (int dy = 0; dy < 2; dy++) {
            float yi = y0 + dy;
            bool vy = (yi >= 0.0f && yi <= 239.0f);
            float wy = 1.0f - fabsf(y - yi);
            #pragma unroll
            for (int dx = 0; dx < 2; dx++) {
                float xi = x0 + dx;
                bool vx = (xi >= 0.0f && xi <= 239.0f);
                float w2v = (vy && vx) ? (1.0f - fabsf(x - xi)) * wy : 0.0f;
                int ci = (dy*2 + dx)*4;
                float xg1 = (float)(int)xi * (float)(2.0/239.0) - 1.0f;
                float yg1 = (float)(int)yi * (float)(2.0/239.0) - 1.0f;
                float gxr = c*xg1 - s*yg1;
                float gyr = s*xg1 + c*yg1;
                float xx = (gxr + 1.0f)*0.5f*239.0f;
                float yy = (gyr + 1.0f)*0.5f*239.0f;
                float xx0 = floorf(xx), yy0 = floorf(yy);
                #pragma unroll
                for (int dy1 = 0; dy1 < 2; dy1++) {
                    float syi = yy0 + dy1;
                    bool v1y = (syi >= 120.0f && syi < 220.0f);
                    float wy1 = 1.0f - fabsf(yy - syi);
                    #pragma unroll
                    for (int dx1 = 0; dx1 < 2; dx1++) {
                        float sxi = xx0 + dx1;
                        bool v1 = v1y && (sxi >= 70.0f && sxi < 170.0f);
                        float w1v = v1 ? (1.0f - fabsf(xx - sxi)) * wy1 : 0.0f;
                        float wt = w2v * w1v;
                        soff[ci + dy1*2 + dx1] = v1 ? ((int)syi - 120)*VR + ((int)sxi - 70) : 0;
                        sw[ci + dy1*2 + dx1] = wt;
                        wsum += wt;
                    }
                }
            }
        }
    }

    if (wsum <= 0.0f) {
        #pragma unroll
        for (int cc = 0; cc < NPL; cc++) o[(size_t)cc*MLSQ] = 0.0f;
        return;
    }
    float acc[NPL];
    #pragma unroll
    for (int cc = 0; cc < NPL; cc++) acc[cc] = 0.0f;
    #pragma unroll
    for (int k = 0; k < 16; k++) {
        float w = sw[k];
        if (w == 0.0f) continue;
        const float* pb = pl + (size_t)soff[k]*CPAD;
        float4 a0 = *(const float4*)(pb + 0);
        float4 a1 = *(const float4*)(pb + 4);
        float4 a2 = *(const float4*)(pb + 8);
        float4 a3 = *(const float4*)(pb + 12);
        float2 a4 = *(const float2*)(pb + 16);
        acc[0]  += fminf(a0.x, 1.0f) * w;
        acc[1]  += fminf(a0.y, 1.0f) * w;
        acc[2]  += fminf(a0.z / 5.0f, 1.0f) * w;
        acc[3]  += fminf(a0.w / 5.0f, 1.0f) * w;
        acc[4]  += fminf(a1.x / 5.0f, 1.0f) * w;
        acc[5]  += fminf(a1.y / 5.0f, 1.0f) * w;
        acc[6]  += fminf(a1.z / 5.0f, 1.0f) * w;
        acc[7]  += fminf(a1.w / 5.0f, 1.0f) * w;
        acc[8]  += fminf(a2.x / 5.0f, 1.0f) * w;
        acc[9]  += fminf(a2.y / 5.0f, 1.0f) * w;
        acc[10] += fminf(a2.z / 5.0f, 1.0f) * w;
        acc[11] += fminf(a2.w / 5.0f, 1.0f) * w;
        acc[12] += fminf(a3.x / 5.0f, 1.0f) * w;
        acc[13] += fminf(a3.y / 5.0f, 1.0f) * w;
        acc[14] += fminf(a3.z / 5.0f, 1.0f) * w;
        acc[15] += fminf(a3.w / 5.0f, 1.0f) * w;
        acc[16] += fminf(a4.x / 5.0f, 1.0f) * w;
        acc[17] += fminf(a4.y / 5.0f, 1.0f) * w;
    }
    #pragma unroll
    for (int cc = 0; cc < NPL; cc++) o[(size_t)cc*MLSQ] = acc[cc];
}

// ---- node 4: {updl7 (blocks 0..6719, long)} ∥ {fginit ch6..21 (short, backfills)} ----
__global__ __launch_bounds__(256) void k_node4(const float* __restrict__ I2,
                                               const float* __restrict__ igm,
                                               const float* __restrict__ ws,
                                               const float* __restrict__ ilm,
                                               const int* __restrict__ dones,
                                               const int* __restrict__ updg,
                                               const int* __restrict__ lmb,
                                               float* __restrict__ fl,
                                               float* __restrict__ fg,
                                               float* __restrict__ out,
                                               float* __restrict__ wsm)
{
    __shared__ float red[4][3][16];
    int bid = blockIdx.x;
    if (bid >= NUPDL) {
        // ---- fginit ch6..21 ----
        int fb = bid - NUPDL;
        int idx = (fb % 225)*256 + threadIdx.x;
        int c = 6 + (fb / 225) % 16;
        int b = fb / (225*16);
        fginit_block(igm, dones, updg, lmb, fg, out, wsm, b, c, idx);
        return;
    }
    // ---- updl7 ----
    int bx = bid & 3;                                // 0..3 col tile
    int gi = (bid >> 2) % 60;                        // 0..59 (4-row group)
    int bz = bid / 240;
    int b = bz / 7, g = bz % 7;
    int lane = threadIdx.x & 63, wv = threadIdx.x >> 6;
    int j0 = (bx < 3) ? bx*64 : 176;                 // tile 3 overlaps tile 2 (benign)
    int j = j0 + lane;
    int i = gi*4 + wv;
    int idx = i*ML + j;

    int ncl, cl[4];
    switch (g) {
        case 0:  ncl = 1; cl[0] = 0; cl[1] = 0; cl[2] = 0; cl[3] = 0; break;
        case 1:  ncl = 3; cl[0] = 1; cl[1] = 2; cl[2] = 3; cl[3] = 0; break;
        case 2:  ncl = 2; cl[0] = 4; cl[1] = 5; cl[2] = 0; cl[3] = 0; break;
        default: ncl = 4; { int cc0 = 6 + (g-3)*4;
                 cl[0] = cc0; cl[1] = cc0+1; cl[2] = cc0+2; cl[3] = cc0+3; } break;
    }
    bool hasG = (g <= 2);

    const float* lmsrc = ilm + (size_t)b*CHL*MLSQ;
    float* lm = fl + (size_t)b*CHL*MLSQ;
    int y0 = lmb[b*4+0], x0 = lmb[b*4+2];            // %4==0 holds for this problem
    bool zeroWin = wsm[WS_FLAGS + b*4 + 1] > 0.5f;
    int lastUpd = (int)wsm[WS_FLAGS + b*4 + 2];

    float S[4];
    #pragma unroll
    for (int q = 0; q < 4; q++) {
        int c = cl[q];
        S[q] = (q < ncl && c != 2) ? lmsrc[c*MLSQ + idx] : 0.0f;
    }

    bool writer = hasG && (wv == 0) && ((lane & 3) == 0);
    int cx = lane >> 2;
    int cellY = (y0 >> 2) + gi;
    int cellX = (x0 >> 2) + (j0 >> 2) + cx;
    float W[3];
    if (writer) {
        #pragma unroll
        for (int q = 0; q < 3; q++)
            if (q < ncl)
                W[q] = wsm[WS_CACHE + ((size_t)b*6 + cl[q])*MLSQ + cellY*ML + cellX];
    }

    for (int t = 0; t < TT; t++) {
        int bt = b*TT + t;
        bool done = dones[bt] != 0;
        bool upd  = updg[bt] != 0;
        const float* src = I2 + (size_t)bt*NPL*MLSQ;
        float* mf = out + (size_t)bt*CHMF*MLSQ;

        float pooled = -3.0e38f;
        if (g == 0) {
            for (int di = -1; di <= 1; di++) {
                int ii = i + di; if (ii < 0 || ii >= ML) continue;
                for (int dj = -1; dj <= 1; dj++) {
                    int jj = j + dj; if (jj < 0 || jj >= ML) continue;
                    pooled = fmaxf(pooled, src[ii*ML + jj]);
                }
            }
        }
        const float* sc = wsm + WS_SCAL + bt*8;
        float acx = sc[4], acy = sc[5];
        float ddx = (float)j - acx, ddy = (float)i - acy;
        float d2 = ddx*ddx + ddy*ddy;
        float curr = (d2 <= 4.0f) ? 1.0f : 0.0f;
        float bc   = (d2 <= 1600.0f) ? 1.0f : 0.0f;

        size_t goff = (size_t)(y0+i)*MG + (x0+j);
        bool wrG = (t == lastUpd) && !zeroWin;

        #pragma unroll
        for (int q = 0; q < 4; q++) {
            if (q >= ncl) continue;
            int c = cl[q];
            if (done) S[q] = 0.0f;
            float nv;
            if      (c == 0) nv = fmaxf(S[q], pooled);
            else if (c == 1) nv = fmaxf(S[q], src[MLSQ + idx]);
            else if (c == 2) nv = curr;
            else if (c == 3) nv = fmaxf(S[q], curr);
            else if (c == 4) nv = fmaxf(S[q], bc);
            else if (c == 5) nv = S[q];
            else             nv = fmaxf(S[q], src[(size_t)(c-4)*MLSQ + idx]);
            S[q] = nv;
            mf[(size_t)(c < 6 ? c : c + 6)*MLSQ + idx] = nv;
            if (wrG) fg[((size_t)b*CHL + c)*MGSQ + goff] = nv;
        }

        if (hasG) {
            #pragma unroll
            for (int q = 0; q < 3; q++) {
                if (q >= ncl) continue;
                float v = S[q];
                v = fmaxf(v, __shfl_xor(v, 1, 64));
                v = fmaxf(v, __shfl_xor(v, 2, 64));
                if ((lane & 3) == 0) red[wv][q][cx] = v;
            }
            __syncthreads();
            if (writer) {
                #pragma unroll
                for (int q = 0; q < 3; q++) {
                    if (q >= ncl) continue;
                    if (done) W[q] = 0.0f;
                    if (upd)  W[q] = fmaxf(fmaxf(red[0][q][cx], red[1][q][cx]),
                                           fmaxf(red[2][q][cx], red[3][q][cx]));
                    mf[(size_t)(6 + cl[q])*MLSQ + cellY*ML + cellX] = W[q];
                }
            }
            __syncthreads();
        }
    }
    #pragma unroll
    for (int q = 0; q < 4; q++)
        if (q < ncl) lm[(size_t)cl[q]*MLSQ + idx] = S[q];
}

extern "C" void kernel_launch(void* const* d_in, const int* in_sizes, int n_in,
                              void* d_out, int out_size, void* d_ws, size_t ws_size,
                              hipStream_t stream)
{
    const float* obs   = (const float*)d_in[0];
    const float* pd    = (const float*)d_in[1];
    const float* cam   = (const float*)d_in[2];
    const float* ilm   = (const float*)d_in[3];
    const float* igm   = (const float*)d_in[4];
    const float* ilp   = (const float*)d_in[5];
    const float* org   = (const float*)d_in[7];
    const int*   dones = (const int*)d_in[8];
    const int*   updg  = (const int*)d_in[9];
    const int*   lmb   = (const int*)d_in[10];
    float* out = (float*)d_out;
    float* ws  = (float*)d_ws;

    float* fl     = out + OFF_FL;
    float* fg     = out + OFF_FG;
    float* planes = ws + WS_PLANES;
    float* I2v    = ws + WS_I2;

    k_node1<<<1 + 75*BB*TT + 225*6*BB, 256, 0, stream>>>(obs, cam, pd, ilp, org, lmb,
                                                         dones, updg, igm, fg, out, ws);
    k_splat2<<<NSPLAT, 256, 0, stream>>>(ws, planes);
    k_gs<<<3600, 256, 0, stream>>>(planes, ws, I2v);
    k_node4<<<NUPDL + 225*16*BB, 256, 0, stream>>>(I2v, igm, ws, ilm, dones, updg, lmb,
                                                   fl, fg, out, ws);
}

// Round 12
// 336.913 us; speedup vs baseline: 1.1313x; 1.1313x over previous
//
#include <hip/hip_runtime.h>
#include <math.h>

#ifndef M_PI
#define M_PI 3.14159265358979323846
#endif

// ---- problem constants ----
#define BB 4
#define TT 4
#define NSEM 16
#define CHL 22            // NC + NUM_SEM
#define CHMF 28           // NC + NC + NUM_SEM
#define ML 240
#define MG 960
#define VR 100
#define HS 120            // FRAME_H/DU
#define WSW 160           // FRAME_W/DU
#define NPL 18            // plane channels: 0=occ,1=exp,2..17=sem
#define CPAD 24           // padded floats per cell (96 B, float4-aligned)
#define MLSQ (ML*ML)      // 57600
#define MGSQ (MG*MG)      // 921600
#define VRSQ (VR*VR)      // 10000
#define PPT (HS*WSW)      // 19200 points per (b,t)
#define NPART 12          // row-bands for LDS splat
#define PR 9              // rows per band (12*9=108 >= 100)
#define NGRP 5            // splat channel groups
#define NSPLAT (BB*TT*NPART*NGRP)   // 960 splat blocks

// ---- output layout (floats) ----
#define SZ_MF (BB*TT*CHMF*MLSQ)
#define SZ_FL (BB*CHL*MLSQ)
#define SZ_FG (BB*CHL*MGSQ)
#define OFF_FL SZ_MF
#define OFF_FG (OFF_FL + SZ_FL)
#define OFF_LP (OFF_FG + SZ_FG)
#define OFF_GP (OFF_LP + BB*TT*3)
#define OFF_LMB (OFF_GP + BB*TT*3)
#define OFF_ORG (OFF_LMB + BB*TT*4)

// ---- ws layout (floats) ----
#define WS_SCAL 0                                   // (b*TT+t)*8: c,s,stx,sty,acx,acy
#define WS_FLAGS (WS_SCAL + BB*TT*8)                // b*4: anyDone, zeroWin, lastUpd
#define WS_AABB (WS_FLAGS + 4*BB)                   // (b*TT+t)*4: ilo,ihi,jlo,jhi
#define WS_CACHE (WS_AABB + 4*BB*TT)                // B*6*240*240 init gmax cache
#define WS_PLANES (WS_CACHE + BB*6*MLSQ)            // B*T*10000*24 channel-innermost
#define WS_I2 (WS_PLANES + BB*TT*VRSQ*CPAD)         // B*T*18*240*240
#define PTSN (BB*TT*PPT)
#define WS_GY (WS_I2 + BB*TT*NPL*MLSQ)
#define WS_GX (WS_GY + PTSN)
#define WS_WZA (WS_GX + PTSN)
#define WS_WZL (WS_WZA + PTSN)
#define WS_SEMDS (WS_WZL + PTSN)                    // B*T*16*PPT

// ---- node 1: {poseall (block 0)} ∥ {prep (blocks 1..1200)} ----
__global__ __launch_bounds__(256) void k_stage1(const float* __restrict__ obs,
                                                const float* __restrict__ cam,
                                                const float* __restrict__ pd,
                                                const float* __restrict__ ilp,
                                                const float* __restrict__ org,
                                                const int* __restrict__ lmb,
                                                const int* __restrict__ dones,
                                                const int* __restrict__ updg,
                                                float* __restrict__ out,
                                                float* __restrict__ ws)
{
    if (blockIdx.x == 0) {
        int i = threadIdx.x;
        if (i < BB*TT) {
            int b = i / TT, t = i % TT;
            for (int k = 0; k < 4; k++) out[OFF_LMB + (b*TT+t)*4 + k] = (float)lmb[b*4+k];
            for (int k = 0; k < 3; k++) out[OFF_ORG + (b*TT+t)*3 + k] = org[b*3+k];
        }
        if (i >= BB) return;
        int b = i;
        float p0 = ilp[b*3+0], p1 = ilp[b*3+1], p2 = ilp[b*3+2];
        const float D2R = 0.017453292519943295f;
        int lastDone = -1, lastUpd = -1;
        for (int t = 0; t < TT; t++) {
            if (dones[b*TT+t]) { p0 = 6.0f; p1 = 6.0f; p2 = 0.0f; lastDone = t; }
            if (updg[b*TT+t]) lastUpd = t;
            float tr = p2 * D2R;
            float c0 = cosf(tr), s0 = sinf(tr);
            float q0 = pd[(b*TT+t)*3+0], q1 = pd[(b*TT+t)*3+1], q2 = pd[(b*TT+t)*3+2];
            float nx = p0 + q0*c0 - q1*s0;
            float ny = p1 + q0*s0 + q1*c0;
            float a  = p2 + q2*57.29577951308232f + 180.0f;
            float m  = fmodf(a, 360.0f); if (m < 0.0f) m += 360.0f;
            float nt = m - 180.0f;
            p0 = nx; p1 = ny; p2 = nt;
            out[OFF_LP + (b*TT+t)*3+0] = nx;
            out[OFF_LP + (b*TT+t)*3+1] = ny;
            out[OFF_LP + (b*TT+t)*3+2] = nt;
            out[OFF_GP + (b*TT+t)*3+0] = nx + org[b*3+0];
            out[OFF_GP + (b*TT+t)*3+1] = ny + org[b*3+1];
            out[OFF_GP + (b*TT+t)*3+2] = nt + org[b*3+2];
            float th = (90.0f - nt) * D2R;
            float ax = nx*100.0f/5.0f, ay = ny*100.0f/5.0f;
            float cth = cosf(th), sth = sinf(th);
            float stxv = -(ax - 120.0f)/120.0f;
            float styv = -(ay - 120.0f)/120.0f;
            float* sc = ws + WS_SCAL + (b*TT+t)*8;
            sc[0] = cth;
            sc[1] = sth;
            sc[2] = stxv;
            sc[3] = styv;
            sc[4] = ax;
            sc[5] = ay;
            // AABB of active (nonzero) gs output pixels: inverse-map source box corners
            float imin = 1e9f, imax = -1e9f, jmin = 1e9f, jmax = -1e9f;
            #pragma unroll
            for (int q = 0; q < 4; q++) {
                float cx = (q & 1) ? 170.0f : 69.0f;
                float cy = (q & 2) ? 220.0f : 119.0f;
                float dj =  cth*(cx - 119.5f) + sth*(cy - 119.5f);
                float di = -sth*(cx - 119.5f) + cth*(cy - 119.5f);
                float jv = 119.5f + dj - stxv*119.5f;
                float iv = 119.5f + di - styv*119.5f;
                imin = fminf(imin, iv); imax = fmaxf(imax, iv);
                jmin = fminf(jmin, jv); jmax = fmaxf(jmax, jv);
            }
            float* ab = ws + WS_AABB + (b*TT+t)*4;
            ab[0] = floorf(imin) - 3.0f;
            ab[1] = ceilf(imax) + 3.0f;
            ab[2] = floorf(jmin) - 3.0f;
            ab[3] = ceilf(jmax) + 3.0f;
        }
        ws[WS_FLAGS + b*4 + 0] = (lastDone >= 0) ? 1.0f : 0.0f;
        ws[WS_FLAGS + b*4 + 1] = (lastUpd < lastDone) ? 1.0f : 0.0f;
        ws[WS_FLAGS + b*4 + 2] = (float)lastUpd;
        return;
    }
    // ---- prep ----
    int bb = blockIdx.x - 1;
    int bt = bb / 75;
    int b = bt / TT;
    int p = (bb % 75)*256 + threadIdx.x;             // < 19200
    int h = p / WSW, w = p % WSW;
    size_t pi = (size_t)bt*PPT + p;
    const float* ob = obs + (size_t)bt * 20 * 480 * 640;
    float d = ob[(size_t)(3*480 + 4*h)*640 + 4*w];
    if (!(d >= 50.0f && d <= 350.0f)) { ws[WS_GY + pi] = -1000.0f; return; }

    double fd = 640.0 / (2.0 * tan((79.0 * M_PI / 180.0) * 0.5));
    float ff  = (float)fd;
    float xsv = (float)(4*w - 320) / ff;
    float zrv = (240.0f - (float)(4*h)) / ff;
    float elev = atan2f(cam[b*16+9], cam[b*16+10]);
    float ce = cosf(elev), se = sinf(elev);
    float up  = d * zrv;
    float fwd = d*ce + up*se;
    float hgt = -d*se + up*ce + 88.0f;
    float gx = (d*xsv)/5.0f + 50.0f;
    float gy = fwd/5.0f;
    float gz = hgt/5.0f + 8.0f;                      // - ZMIN

    float z0 = floorf(gz);
    float wza = 0.0f, wzl = 0.0f;
    #pragma unroll
    for (int dz = 0; dz < 2; dz++) {
        float zi = z0 + dz;
        float wz = 1.0f - fabsf(gz - zi);
        if (zi >= 0.0f && zi < 80.0f) {
            wzl += wz;
            if (zi >= 13.0f && zi < 25.0f) wza += wz;
        }
    }
    if (wzl == 0.0f && wza == 0.0f) { ws[WS_GY + pi] = -1000.0f; return; }

    ws[WS_GY + pi]  = gy;
    ws[WS_GX + pi]  = gx;
    ws[WS_WZA + pi] = wza;
    ws[WS_WZL + pi] = wzl;

    if (wza > 0.0f) {
        const float* sb = ob + (size_t)4*480*640 + (size_t)(4*h)*640 + 4*w;
        float* so = ws + WS_SEMDS + (size_t)bt*NSEM*PPT + p;
        #pragma unroll
        for (int k = 0; k < NSEM; k++) {
            float s = 0.0f;
            #pragma unroll
            for (int r = 0; r < 4; r++) {
                const float4 v = *(const float4*)(sb + (size_t)k*480*640 + r*640);
                s += v.x + v.y + v.z + v.w;
            }
            so[(size_t)k*PPT] = s * 0.0625f;
        }
    }
}

// ---- node 2: {splat (blocks 0..959)} ∥ {fginit all 22 ch} ----
__global__ __launch_bounds__(256) void k_stage2(const float* __restrict__ igm,
                                                const int* __restrict__ dones,
                                                const int* __restrict__ lmb,
                                                float* __restrict__ planes,
                                                float* __restrict__ fg,
                                                float* __restrict__ out,
                                                float* __restrict__ ws)
{
    __shared__ float acc[4*PR*VR];                   // 14.4 KB
    int bid = blockIdx.x;
    if (bid < NSPLAT) {
        // bid = (grp*NPART + part)*16 + bt
        int bt = bid & 15;
        int part = (bid >> 4) % NPART;
        int grp = bid / (16*NPART);
        int rlo = part * PR;
        int c0  = (grp == 0) ? 0 : (2 + 4*(grp-1));
        int nch = (grp == 0) ? 2 : 4;
        for (int e = threadIdx.x; e < nch*PR*VR; e += 256) acc[e] = 0.0f;
        __syncthreads();

        const float* gyA  = ws + WS_GY  + (size_t)bt*PPT;
        const float* gxA  = ws + WS_GX  + (size_t)bt*PPT;
        const float* wzaA = ws + WS_WZA + (size_t)bt*PPT;
        const float* wzlA = ws + WS_WZL + (size_t)bt*PPT;
        const float* semA = ws + WS_SEMDS + (size_t)bt*NSEM*PPT + (size_t)(c0-2)*PPT;

        for (int p = threadIdx.x; p < PPT; p += 256) {
            float gy = gyA[p];
            float y0 = floorf(gy);
            if (y0 > (float)(rlo + PR - 1) || y0 + 1.0f < (float)rlo) continue;
            float wza = wzaA[p];
            if (grp != 0 && wza <= 0.0f) continue;
            float gx  = gxA[p];
            float x0 = floorf(gx);
            float sem[4];
            if (grp != 0) {
                #pragma unroll
                for (int k = 0; k < 4; k++) sem[k] = semA[(size_t)k*PPT + p];
            }
            float wzl = (grp == 0) ? wzlA[p] : 0.0f;
            #pragma unroll
            for (int dy = 0; dy < 2; dy++) {
                float yi = y0 + dy;
                if (!(yi >= 0.0f && yi < 100.0f)) continue;
                int r = (int)yi - rlo;
                if (r < 0 || r >= PR) continue;
                float wy = 1.0f - fabsf(gy - yi);
                #pragma unroll
                for (int dx = 0; dx < 2; dx++) {
                    float xi = x0 + dx;
                    if (!(xi >= 0.0f && xi < 100.0f)) continue;
                    float wxy = (1.0f - fabsf(gx - xi)) * wy;
                    if (wxy <= 0.0f) continue;
                    int cell = r*VR + (int)xi;
                    if (grp == 0) {
                        if (wza > 0.0f) atomicAdd(&acc[cell], wza*wxy);
                        if (wzl > 0.0f) atomicAdd(&acc[PR*VR + cell], wzl*wxy);
                    } else {
                        #pragma unroll
                        for (int k = 0; k < 4; k++) {
                            float sv = sem[k];
                            if (sv != 0.0f) atomicAdd(&acc[k*PR*VR + cell], sv*wza*wxy);
                        }
                    }
                }
            }
        }
        __syncthreads();

        int nrows = 100 - rlo; if (nrows > PR) nrows = PR;
        if (nrows <= 0) return;
        float* pl = planes + (size_t)bt*VRSQ*CPAD;
        for (int e = threadIdx.x; e < nch*nrows*VR; e += 256) {
            int c = e / (nrows*VR);
            int rc = e % (nrows*VR);
            int r = rc / VR, x = rc % VR;
            pl[(size_t)((rlo + r)*VR + x)*CPAD + (c0 + c)] = acc[c*PR*VR + r*VR + x];
        }
        return;
    }
    // ---- fginit ----
    int fb = bid - NSPLAT;
    int blk = fb % 225;
    int c = (fb / 225) % CHL;
    int b = fb / (225*CHL);
    int idx = blk*256 + threadIdx.x;
    int i = idx / ML, j = idx % ML;                  // 4x4 cell coords
    bool anyDone = ws[WS_FLAGS + b*4 + 0] > 0.5f;
    bool zeroWin = ws[WS_FLAGS + b*4 + 1] > 0.5f;
    int lastUpd  = (int)ws[WS_FLAGS + b*4 + 2];
    int y0 = lmb[b*4+0], x0 = lmb[b*4+2];
    int iy0 = y0 >> 2, ix0 = x0 >> 2;
    bool inWin = (i >= iy0) && (i < iy0 + ML/4) && (j >= ix0) && (j < ix0 + ML/4);

    size_t base = ((size_t)b*CHL + c)*MGSQ + (size_t)(4*i)*MG + 4*j;
    const float* g = igm + base;
    float* go = fg + base;

    int act;                                         // 0=copy 1=zeros 2=skip(updl writes)
    if (inWin) act = zeroWin ? 1 : ((lastUpd >= 0) ? 2 : (anyDone ? 1 : 0));
    else       act = anyDone ? 1 : 0;

    if (c < 6) {
        float m = -3.0e38f;
        #pragma unroll
        for (int r = 0; r < 4; r++) {
            float4 q = *(const float4*)(g + (size_t)r*MG);
            if (act == 0) *(float4*)(go + (size_t)r*MG) = q;
            else if (act == 1) *(float4*)(go + (size_t)r*MG) = make_float4(0,0,0,0);
            m = fmaxf(m, fmaxf(fmaxf(q.x, q.y), fmaxf(q.z, q.w)));
        }
        ws[WS_CACHE + ((size_t)b*6 + c)*MLSQ + idx] = m;
        if (!inWin) {
            float v = m;
            for (int t = 0; t < TT; t++) {
                if (dones[b*TT+t]) v = 0.0f;
                out[(size_t)(b*TT+t)*CHMF*MLSQ + (6+c)*MLSQ + idx] = v;
            }
        }
    } else {
        if (act == 2) return;
        if (act == 1) {
            float4 z = make_float4(0,0,0,0);
            #pragma unroll
            for (int r = 0; r < 4; r++) *(float4*)(go + (size_t)r*MG) = z;
        } else {
            #pragma unroll
            for (int r = 0; r < 4; r++)
                *(float4*)(go + (size_t)r*MG) = *(const float4*)(g + (size_t)r*MG);
        }
    }
}

// ---- node 3: fused gs2∘gs1, 18 channels, 16x16 tiles with AABB block-skip ----
__global__ __launch_bounds__(256) void k_gs(const float* __restrict__ planes,
                                            const float* __restrict__ ws,
                                            float* __restrict__ I2)
{
    int bt = blockIdx.z;
    const float* ab = ws + WS_AABB + bt*4;
    int ilo = (int)ab[0], ihi = (int)ab[1], jlo = (int)ab[2], jhi = (int)ab[3];
    int r0 = blockIdx.y*16, q0 = blockIdx.x*16;
    // skip tiles with no pixel in [ilo-2,ihi+2]x[jlo-2,jhi+2] (updl reads stay inside)
    if (r0+15 < ilo-2 || r0 > ihi+2 || q0+15 < jlo-2 || q0 > jhi+2) return;

    int i = r0 + (threadIdx.x >> 4);
    int j = q0 + (threadIdx.x & 15);
    int idx = i*ML + j;
    const float* sc = ws + WS_SCAL + bt*8;
    float c = sc[0], s = sc[1], stx = sc[2], sty = sc[3];
    float* o = I2 + (size_t)bt*NPL*MLSQ + idx;
    const float* pl = planes + (size_t)bt*VRSQ*CPAD;

    int   soff[16];
    float sw[16];
    float wsum = 0.0f;
    {
        float xg = (float)j * (float)(2.0/239.0) - 1.0f + stx;
        float yg = (float)i * (float)(2.0/239.0) - 1.0f + sty;
        float x = (xg + 1.0f)*0.5f*239.0f;
        float y = (yg + 1.0f)*0.5f*239.0f;
        float x0 = floorf(x), y0 = floorf(y);
        #pragma unroll
        for (int dy = 0; dy < 2; dy++) {
            float yi = y0 + dy;
            bool vy = (yi >= 0.0f && yi <= 239.0f);
            float wy = 1.0f - fabsf(y - yi);
            #pragma unroll
            for (int dx = 0; dx < 2; dx++) {
                float xi = x0 + dx;
                bool vx = (xi >= 0.0f && xi <= 239.0f);
                float w2v = (vy && vx) ? (1.0f - fabsf(x - xi)) * wy : 0.0f;
                int ci = (dy*2 + dx)*4;
                float xg1 = (float)(int)xi * (float)(2.0/239.0) - 1.0f;
                float yg1 = (float)(int)yi * (float)(2.0/239.0) - 1.0f;
                float gxr = c*xg1 - s*yg1;
                float gyr = s*xg1 + c*yg1;
                float xx = (gxr + 1.0f)*0.5f*239.0f;
                float yy = (gyr + 1.0f)*0.5f*239.0f;
                float xx0 = floorf(xx), yy0 = floorf(yy);
                #pragma unroll
                for (int dy1 = 0; dy1 < 2; dy1++) {
                    float syi = yy0 + dy1;
                    bool v1y = (syi >= 120.0f && syi < 220.0f);
                    float wy1 = 1.0f - fabsf(yy - syi);
                    #pragma unroll
                    for (int dx1 = 0; dx1 < 2; dx1++) {
                        float sxi = xx0 + dx1;
                        bool v1 = v1y && (sxi >= 70.0f && sxi < 170.0f);
                        float w1v = v1 ? (1.0f - fabsf(xx - sxi)) * wy1 : 0.0f;
                        float wt = w2v * w1v;
                        soff[ci + dy1*2 + dx1] = v1 ? ((int)syi - 120)*VR + ((int)sxi - 70) : 0;
                        sw[ci + dy1*2 + dx1] = wt;
                        wsum += wt;
                    }
                }
            }
        }
    }

    if (wsum <= 0.0f) {
        #pragma unroll
        for (int cc = 0; cc < NPL; cc++) o[(size_t)cc*MLSQ] = 0.0f;
        return;
    }
    float acc[NPL];
    #pragma unroll
    for (int cc = 0; cc < NPL; cc++) acc[cc] = 0.0f;
    #pragma unroll
    for (int k = 0; k < 16; k++) {
        float w = sw[k];
        if (w == 0.0f) continue;
        const float* pb = pl + (size_t)soff[k]*CPAD;
        float4 a0 = *(const float4*)(pb + 0);
        float4 a1 = *(const float4*)(pb + 4);
        float4 a2 = *(const float4*)(pb + 8);
        float4 a3 = *(const float4*)(pb + 12);
        float2 a4 = *(const float2*)(pb + 16);
        acc[0]  += fminf(a0.x, 1.0f) * w;
        acc[1]  += fminf(a0.y, 1.0f) * w;
        acc[2]  += fminf(a0.z / 5.0f, 1.0f) * w;
        acc[3]  += fminf(a0.w / 5.0f, 1.0f) * w;
        acc[4]  += fminf(a1.x / 5.0f, 1.0f) * w;
        acc[5]  += fminf(a1.y / 5.0f, 1.0f) * w;
        acc[6]  += fminf(a1.z / 5.0f, 1.0f) * w;
        acc[7]  += fminf(a1.w / 5.0f, 1.0f) * w;
        acc[8]  += fminf(a2.x / 5.0f, 1.0f) * w;
        acc[9]  += fminf(a2.y / 5.0f, 1.0f) * w;
        acc[10] += fminf(a2.z / 5.0f, 1.0f) * w;
        acc[11] += fminf(a2.w / 5.0f, 1.0f) * w;
        acc[12] += fminf(a3.x / 5.0f, 1.0f) * w;
        acc[13] += fminf(a3.y / 5.0f, 1.0f) * w;
        acc[14] += fminf(a3.z / 5.0f, 1.0f) * w;
        acc[15] += fminf(a3.w / 5.0f, 1.0f) * w;
        acc[16] += fminf(a4.x / 5.0f, 1.0f) * w;
        acc[17] += fminf(a4.y / 5.0f, 1.0f) * w;
    }
    #pragma unroll
    for (int cc = 0; cc < NPL; cc++) o[(size_t)cc*MLSQ] = acc[cc];
}

// ---- node 4: channel-group-split temporal evolution with AABB read-guards ----
// groups: 0={0(pool)}, 1={1,2,3}, 2={4,5}, 3..6 = sem quads
__global__ __launch_bounds__(256) void k_updl7(const float* __restrict__ I2,
                                               const float* __restrict__ ws,
                                               const float* __restrict__ ilm,
                                               const int* __restrict__ dones,
                                               const int* __restrict__ updg,
                                               const int* __restrict__ lmb,
                                               float* __restrict__ fl,
                                               float* __restrict__ fg,
                                               float* __restrict__ out)
{
    int bz = blockIdx.z;
    int b = bz / 7, g = bz % 7;
    int gi = blockIdx.y;                             // 0..59 (4-row group)
    int bx = blockIdx.x;                             // 0..3 col tile
    int lane = threadIdx.x & 63, wv = threadIdx.x >> 6;
    int j0 = (bx < 3) ? bx*64 : 176;                 // tile 3 overlaps tile 2 (benign)
    int j = j0 + lane;
    int i = gi*4 + wv;
    int idx = i*ML + j;

    int ncl, cl[4];
    switch (g) {
        case 0:  ncl = 1; cl[0] = 0; cl[1] = 0; cl[2] = 0; cl[3] = 0; break;
        case 1:  ncl = 3; cl[0] = 1; cl[1] = 2; cl[2] = 3; cl[3] = 0; break;
        case 2:  ncl = 2; cl[0] = 4; cl[1] = 5; cl[2] = 0; cl[3] = 0; break;
        default: ncl = 4; { int cc0 = 6 + (g-3)*4;
                 cl[0] = cc0; cl[1] = cc0+1; cl[2] = cc0+2; cl[3] = cc0+3; } break;
    }
    bool hasG = (g <= 2);

    __shared__ float red[4][3][16];

    const float* lmsrc = ilm + (size_t)b*CHL*MLSQ;
    float* lm = fl + (size_t)b*CHL*MLSQ;
    int y0 = lmb[b*4+0], x0 = lmb[b*4+2];            // %4==0 holds for this problem
    bool zeroWin = ws[WS_FLAGS + b*4 + 1] > 0.5f;
    int lastUpd = (int)ws[WS_FLAGS + b*4 + 2];

    float S[4];
    #pragma unroll
    for (int q = 0; q < 4; q++) {
        int c = cl[q];
        S[q] = (q < ncl && c != 2) ? lmsrc[c*MLSQ + idx] : 0.0f;
    }

    bool writer = hasG && (wv == 0) && ((lane & 3) == 0);
    int cx = lane >> 2;
    int cellY = (y0 >> 2) + gi;
    int cellX = (x0 >> 2) + (j0 >> 2) + cx;
    float W[3];
    if (writer) {
        #pragma unroll
        for (int q = 0; q < 3; q++)
            if (q < ncl)
                W[q] = ws[WS_CACHE + ((size_t)b*6 + cl[q])*MLSQ + cellY*ML + cellX];
    }

    for (int t = 0; t < TT; t++) {
        int bt = b*TT + t;
        bool done = dones[bt] != 0;
        bool upd  = updg[bt] != 0;
        const float* src = I2 + (size_t)bt*NPL*MLSQ;
        float* mf = out + (size_t)bt*CHMF*MLSQ;
        const float* ab = ws + WS_AABB + bt*4;
        int ilo = (int)ab[0], ihi = (int)ab[1], jlo = (int)ab[2], jhi = (int)ab[3];
        bool inA = (i >= ilo) && (i <= ihi) && (j >= jlo) && (j <= jhi);

        float pooled = 0.0f;
        if (g == 0) {
            bool inP = (i >= ilo-1) && (i <= ihi+1) && (j >= jlo-1) && (j <= jhi+1);
            if (inP) {
                pooled = -3.0e38f;
                for (int di = -1; di <= 1; di++) {
                    int ii = i + di; if (ii < 0 || ii >= ML) continue;
                    for (int dj = -1; dj <= 1; dj++) {
                        int jj = j + dj; if (jj < 0 || jj >= ML) continue;
                        pooled = fmaxf(pooled, src[ii*ML + jj]);
                    }
                }
            }
        }
        const float* sc = ws + WS_SCAL + bt*8;
        float acx = sc[4], acy = sc[5];
        float ddx = (float)j - acx, ddy = (float)i - acy;
        float d2 = ddx*ddx + ddy*ddy;
        float curr = (d2 <= 4.0f) ? 1.0f : 0.0f;
        float bc   = (d2 <= 1600.0f) ? 1.0f : 0.0f;

        size_t goff = (size_t)(y0+i)*MG + (x0+j);
        bool wrG = (t == lastUpd) && !zeroWin;

        #pragma unroll
        for (int q = 0; q < 4; q++) {
            if (q >= ncl) continue;
            int c = cl[q];
            if (done) S[q] = 0.0f;
            float nv;
            if      (c == 0) nv = fmaxf(S[q], pooled);
            else if (c == 1) nv = fmaxf(S[q], inA ? src[MLSQ + idx] : 0.0f);
            else if (c == 2) nv = curr;
            else if (c == 3) nv = fmaxf(S[q], curr);
            else if (c == 4) nv = fmaxf(S[q], bc);
            else if (c == 5) nv = S[q];
            else             nv = fmaxf(S[q], inA ? src[(size_t)(c-4)*MLSQ + idx] : 0.0f);
            S[q] = nv;
            mf[(size_t)(c < 6 ? c : c + 6)*MLSQ + idx] = nv;
            if (wrG) fg[((size_t)b*CHL + c)*MGSQ + goff] = nv;
        }

        if (hasG) {
            #pragma unroll
            for (int q = 0; q < 3; q++) {
                if (q >= ncl) continue;
                float v = S[q];
                v = fmaxf(v, __shfl_xor(v, 1, 64));
                v = fmaxf(v, __shfl_xor(v, 2, 64));
                if ((lane & 3) == 0) red[wv][q][cx] = v;
            }
            __syncthreads();
            if (writer) {
                #pragma unroll
                for (int q = 0; q < 3; q++) {
                    if (q >= ncl) continue;
                    if (done) W[q] = 0.0f;
                    if (upd)  W[q] = fmaxf(fmaxf(red[0][q][cx], red[1][q][cx]),
                                           fmaxf(red[2][q][cx], red[3][q][cx]));
                    mf[(size_t)(6 + cl[q])*MLSQ + cellY*ML + cellX] = W[q];
                }
            }
            __syncthreads();
        }
    }
    #pragma unroll
    for (int q = 0; q < 4; q++)
        if (q < ncl) lm[(size_t)cl[q]*MLSQ + idx] = S[q];
}

extern "C" void kernel_launch(void* const* d_in, const int* in_sizes, int n_in,
                              void* d_out, int out_size, void* d_ws, size_t ws_size,
                              hipStream_t stream)
{
    const float* obs   = (const float*)d_in[0];
    const float* pd    = (const float*)d_in[1];
    const float* cam   = (const float*)d_in[2];
    const float* ilm   = (const float*)d_in[3];
    const float* igm   = (const float*)d_in[4];
    const float* ilp   = (const float*)d_in[5];
    const float* org   = (const float*)d_in[7];
    const int*   dones = (const int*)d_in[8];
    const int*   updg  = (const int*)d_in[9];
    const int*   lmb   = (const int*)d_in[10];
    float* out = (float*)d_out;
    float* ws  = (float*)d_ws;

    float* fl     = out + OFF_FL;
    float* fg     = out + OFF_FG;
    float* planes = ws + WS_PLANES;
    float* I2v    = ws + WS_I2;

    k_stage1<<<1 + 75*BB*TT, 256, 0, stream>>>(obs, cam, pd, ilp, org, lmb,
                                               dones, updg, out, ws);
    k_stage2<<<NSPLAT + 225*CHL*BB, 256, 0, stream>>>(igm, dones, lmb,
                                                      planes, fg, out, ws);
    k_gs<<<dim3(15, 15, BB*TT), 256, 0, stream>>>(planes, ws, I2v);
    k_updl7<<<dim3(4, 60, BB*7), 256, 0, stream>>>(I2v, ws, ilm, dones, updg, lmb,
                                                   fl, fg, out);
}

// Round 13
// 326.733 us; speedup vs baseline: 1.1665x; 1.0312x over previous
//
#include <hip/hip_runtime.h>
#include <math.h>

#ifndef M_PI
#define M_PI 3.14159265358979323846
#endif

// ---- problem constants ----
#define BB 4
#define TT 4
#define NSEM 16
#define CHL 22            // NC + NUM_SEM
#define CHMF 28           // NC + NC + NUM_SEM
#define ML 240
#define MG 960
#define VR 100
#define HS 120            // FRAME_H/DU
#define WSW 160           // FRAME_W/DU
#define NPL 18            // plane channels: 0=occ,1=exp,2..17=sem
#define CPAD 24           // padded floats per cell (96 B, float4-aligned)
#define MLSQ (ML*ML)      // 57600
#define MGSQ (MG*MG)      // 921600
#define VRSQ (VR*VR)      // 10000
#define PPT (HS*WSW)      // 19200 points per (b,t)
#define NPART 12          // row-bands for LDS splat
#define PR 9              // rows per band (12*9=108 >= 100)
#define NGRP 5            // splat channel groups
#define NSPLAT (BB*TT*NPART*NGRP)   // 960 splat blocks

// ---- output layout (floats) ----
#define SZ_MF (BB*TT*CHMF*MLSQ)
#define SZ_FL (BB*CHL*MLSQ)
#define SZ_FG (BB*CHL*MGSQ)
#define OFF_FL SZ_MF
#define OFF_FG (OFF_FL + SZ_FL)
#define OFF_LP (OFF_FG + SZ_FG)
#define OFF_GP (OFF_LP + BB*TT*3)
#define OFF_LMB (OFF_GP + BB*TT*3)
#define OFF_ORG (OFF_LMB + BB*TT*4)

// ---- ws layout (floats) ----
#define WS_SCAL 0                                   // (b*TT+t)*8: c,s,stx,sty,acx,acy
#define WS_FLAGS (WS_SCAL + BB*TT*8)                // b*4: anyDone, zeroWin, lastUpd
#define WS_AABB (WS_FLAGS + 4*BB)                   // (b*TT+t)*4: ilo,ihi,jlo,jhi
#define WS_CACHE (WS_AABB + 4*BB*TT)                // B*6*240*240 init gmax cache
#define WS_PLANES (WS_CACHE + BB*6*MLSQ)            // B*T*10000*24 channel-innermost
#define WS_I2 (WS_PLANES + BB*TT*VRSQ*CPAD)         // B*T*18*240*240
#define PTSN (BB*TT*PPT)
#define WS_GY (WS_I2 + BB*TT*NPL*MLSQ)
#define WS_GX (WS_GY + PTSN)
#define WS_WZA (WS_GX + PTSN)
#define WS_WZL (WS_WZA + PTSN)
#define WS_SEMDS (WS_WZL + PTSN)                    // B*T*16*PPT

// ---- node 1: {poseall (block 0)} ∥ {prep (blocks 1..1200)} ----
__global__ __launch_bounds__(256) void k_stage1(const float* __restrict__ obs,
                                                const float* __restrict__ cam,
                                                const float* __restrict__ pd,
                                                const float* __restrict__ ilp,
                                                const float* __restrict__ org,
                                                const int* __restrict__ lmb,
                                                const int* __restrict__ dones,
                                                const int* __restrict__ updg,
                                                float* __restrict__ out,
                                                float* __restrict__ ws)
{
    if (blockIdx.x == 0) {
        int i = threadIdx.x;
        if (i < BB*TT) {
            int b = i / TT, t = i % TT;
            for (int k = 0; k < 4; k++) out[OFF_LMB + (b*TT+t)*4 + k] = (float)lmb[b*4+k];
            for (int k = 0; k < 3; k++) out[OFF_ORG + (b*TT+t)*3 + k] = org[b*3+k];
        }
        if (i >= BB) return;
        int b = i;
        float p0 = ilp[b*3+0], p1 = ilp[b*3+1], p2 = ilp[b*3+2];
        const float D2R = 0.017453292519943295f;
        int lastDone = -1, lastUpd = -1;
        for (int t = 0; t < TT; t++) {
            if (dones[b*TT+t]) { p0 = 6.0f; p1 = 6.0f; p2 = 0.0f; lastDone = t; }
            if (updg[b*TT+t]) lastUpd = t;
            float tr = p2 * D2R;
            float c0 = cosf(tr), s0 = sinf(tr);
            float q0 = pd[(b*TT+t)*3+0], q1 = pd[(b*TT+t)*3+1], q2 = pd[(b*TT+t)*3+2];
            float nx = p0 + q0*c0 - q1*s0;
            float ny = p1 + q0*s0 + q1*c0;
            float a  = p2 + q2*57.29577951308232f + 180.0f;
            float m  = fmodf(a, 360.0f); if (m < 0.0f) m += 360.0f;
            float nt = m - 180.0f;
            p0 = nx; p1 = ny; p2 = nt;
            out[OFF_LP + (b*TT+t)*3+0] = nx;
            out[OFF_LP + (b*TT+t)*3+1] = ny;
            out[OFF_LP + (b*TT+t)*3+2] = nt;
            out[OFF_GP + (b*TT+t)*3+0] = nx + org[b*3+0];
            out[OFF_GP + (b*TT+t)*3+1] = ny + org[b*3+1];
            out[OFF_GP + (b*TT+t)*3+2] = nt + org[b*3+2];
            float th = (90.0f - nt) * D2R;
            float ax = nx*100.0f/5.0f, ay = ny*100.0f/5.0f;
            float cth = cosf(th), sth = sinf(th);
            float stxv = -(ax - 120.0f)/120.0f;
            float styv = -(ay - 120.0f)/120.0f;
            float* sc = ws + WS_SCAL + (b*TT+t)*8;
            sc[0] = cth;
            sc[1] = sth;
            sc[2] = stxv;
            sc[3] = styv;
            sc[4] = ax;
            sc[5] = ay;
            // AABB of active (nonzero) gs output pixels: inverse-map source box corners
            float imin = 1e9f, imax = -1e9f, jmin = 1e9f, jmax = -1e9f;
            #pragma unroll
            for (int q = 0; q < 4; q++) {
                float cx = (q & 1) ? 170.0f : 69.0f;
                float cy = (q & 2) ? 220.0f : 119.0f;
                float dj =  cth*(cx - 119.5f) + sth*(cy - 119.5f);
                float di = -sth*(cx - 119.5f) + cth*(cy - 119.5f);
                float jv = 119.5f + dj - stxv*119.5f;
                float iv = 119.5f + di - styv*119.5f;
                imin = fminf(imin, iv); imax = fmaxf(imax, iv);
                jmin = fminf(jmin, jv); jmax = fmaxf(jmax, jv);
            }
            float* ab = ws + WS_AABB + (b*TT+t)*4;
            ab[0] = floorf(imin) - 3.0f;
            ab[1] = ceilf(imax) + 3.0f;
            ab[2] = floorf(jmin) - 3.0f;
            ab[3] = ceilf(jmax) + 3.0f;
        }
        ws[WS_FLAGS + b*4 + 0] = (lastDone >= 0) ? 1.0f : 0.0f;
        ws[WS_FLAGS + b*4 + 1] = (lastUpd < lastDone) ? 1.0f : 0.0f;
        ws[WS_FLAGS + b*4 + 2] = (float)lastUpd;
        return;
    }
    // ---- prep ----
    int bb = blockIdx.x - 1;
    int bt = bb / 75;
    int b = bt / TT;
    int p = (bb % 75)*256 + threadIdx.x;             // < 19200
    int h = p / WSW, w = p % WSW;
    size_t pi = (size_t)bt*PPT + p;
    const float* ob = obs + (size_t)bt * 20 * 480 * 640;
    float d = ob[(size_t)(3*480 + 4*h)*640 + 4*w];
    if (!(d >= 50.0f && d <= 350.0f)) { ws[WS_GY + pi] = -1000.0f; return; }

    double fd = 640.0 / (2.0 * tan((79.0 * M_PI / 180.0) * 0.5));
    float ff  = (float)fd;
    float xsv = (float)(4*w - 320) / ff;
    float zrv = (240.0f - (float)(4*h)) / ff;
    float elev = atan2f(cam[b*16+9], cam[b*16+10]);
    float ce = cosf(elev), se = sinf(elev);
    float up  = d * zrv;
    float fwd = d*ce + up*se;
    float hgt = -d*se + up*ce + 88.0f;
    float gx = (d*xsv)/5.0f + 50.0f;
    float gy = fwd/5.0f;
    float gz = hgt/5.0f + 8.0f;                      // - ZMIN

    float z0 = floorf(gz);
    float wza = 0.0f, wzl = 0.0f;
    #pragma unroll
    for (int dz = 0; dz < 2; dz++) {
        float zi = z0 + dz;
        float wz = 1.0f - fabsf(gz - zi);
        if (zi >= 0.0f && zi < 80.0f) {
            wzl += wz;
            if (zi >= 13.0f && zi < 25.0f) wza += wz;
        }
    }
    if (wzl == 0.0f && wza == 0.0f) { ws[WS_GY + pi] = -1000.0f; return; }

    ws[WS_GY + pi]  = gy;
    ws[WS_GX + pi]  = gx;
    ws[WS_WZA + pi] = wza;
    ws[WS_WZL + pi] = wzl;

    if (wza > 0.0f) {
        const float* sb = ob + (size_t)4*480*640 + (size_t)(4*h)*640 + 4*w;
        float* so = ws + WS_SEMDS + (size_t)bt*NSEM*PPT + p;
        #pragma unroll
        for (int k = 0; k < NSEM; k++) {
            float s = 0.0f;
            #pragma unroll
            for (int r = 0; r < 4; r++) {
                const float4 v = *(const float4*)(sb + (size_t)k*480*640 + r*640);
                s += v.x + v.y + v.z + v.w;
            }
            so[(size_t)k*PPT] = s * 0.0625f;
        }
    }
}

// ---- node 2: {splat (blocks 0..959)} ∥ {fginit all 22 ch} ----
__global__ __launch_bounds__(256) void k_stage2(const float* __restrict__ igm,
                                                const int* __restrict__ dones,
                                                const int* __restrict__ lmb,
                                                float* __restrict__ planes,
                                                float* __restrict__ fg,
                                                float* __restrict__ out,
                                                float* __restrict__ ws)
{
    __shared__ float acc[4*PR*VR];                   // 14.4 KB
    int bid = blockIdx.x;
    if (bid < NSPLAT) {
        // bid = (grp*NPART + part)*16 + bt
        int bt = bid & 15;
        int part = (bid >> 4) % NPART;
        int grp = bid / (16*NPART);
        int rlo = part * PR;
        int c0  = (grp == 0) ? 0 : (2 + 4*(grp-1));
        int nch = (grp == 0) ? 2 : 4;
        for (int e = threadIdx.x; e < nch*PR*VR; e += 256) acc[e] = 0.0f;
        __syncthreads();

        const float* gyA  = ws + WS_GY  + (size_t)bt*PPT;
        const float* gxA  = ws + WS_GX  + (size_t)bt*PPT;
        const float* wzaA = ws + WS_WZA + (size_t)bt*PPT;
        const float* wzlA = ws + WS_WZL + (size_t)bt*PPT;
        const float* semA = ws + WS_SEMDS + (size_t)bt*NSEM*PPT + (size_t)(c0-2)*PPT;

        for (int p = threadIdx.x; p < PPT; p += 256) {
            float gy = gyA[p];
            float y0 = floorf(gy);
            if (y0 > (float)(rlo + PR - 1) || y0 + 1.0f < (float)rlo) continue;
            float wza = wzaA[p];
            if (grp != 0 && wza <= 0.0f) continue;
            float gx  = gxA[p];
            float x0 = floorf(gx);
            float sem[4];
            if (grp != 0) {
                #pragma unroll
                for (int k = 0; k < 4; k++) sem[k] = semA[(size_t)k*PPT + p];
            }
            float wzl = (grp == 0) ? wzlA[p] : 0.0f;
            #pragma unroll
            for (int dy = 0; dy < 2; dy++) {
                float yi = y0 + dy;
                if (!(yi >= 0.0f && yi < 100.0f)) continue;
                int r = (int)yi - rlo;
                if (r < 0 || r >= PR) continue;
                float wy = 1.0f - fabsf(gy - yi);
                #pragma unroll
                for (int dx = 0; dx < 2; dx++) {
                    float xi = x0 + dx;
                    if (!(xi >= 0.0f && xi < 100.0f)) continue;
                    float wxy = (1.0f - fabsf(gx - xi)) * wy;
                    if (wxy <= 0.0f) continue;
                    int cell = r*VR + (int)xi;
                    if (grp == 0) {
                        if (wza > 0.0f) atomicAdd(&acc[cell], wza*wxy);
                        if (wzl > 0.0f) atomicAdd(&acc[PR*VR + cell], wzl*wxy);
                    } else {
                        #pragma unroll
                        for (int k = 0; k < 4; k++) {
                            float sv = sem[k];
                            if (sv != 0.0f) atomicAdd(&acc[k*PR*VR + cell], sv*wza*wxy);
                        }
                    }
                }
            }
        }
        __syncthreads();

        int nrows = 100 - rlo; if (nrows > PR) nrows = PR;
        if (nrows <= 0) return;
        float* pl = planes + (size_t)bt*VRSQ*CPAD;
        for (int e = threadIdx.x; e < nch*nrows*VR; e += 256) {
            int c = e / (nrows*VR);
            int rc = e % (nrows*VR);
            int r = rc / VR, x = rc % VR;
            pl[(size_t)((rlo + r)*VR + x)*CPAD + (c0 + c)] = acc[c*PR*VR + r*VR + x];
        }
        return;
    }
    // ---- fginit ----
    int fb = bid - NSPLAT;
    int blk = fb % 225;
    int c = (fb / 225) % CHL;
    int b = fb / (225*CHL);
    int idx = blk*256 + threadIdx.x;
    int i = idx / ML, j = idx % ML;                  // 4x4 cell coords
    bool anyDone = ws[WS_FLAGS + b*4 + 0] > 0.5f;
    bool zeroWin = ws[WS_FLAGS + b*4 + 1] > 0.5f;
    int lastUpd  = (int)ws[WS_FLAGS + b*4 + 2];
    int y0 = lmb[b*4+0], x0 = lmb[b*4+2];
    int iy0 = y0 >> 2, ix0 = x0 >> 2;
    bool inWin = (i >= iy0) && (i < iy0 + ML/4) && (j >= ix0) && (j < ix0 + ML/4);

    size_t base = ((size_t)b*CHL + c)*MGSQ + (size_t)(4*i)*MG + 4*j;
    const float* g = igm + base;
    float* go = fg + base;

    int act;                                         // 0=copy 1=zeros 2=skip(updl writes)
    if (inWin) act = zeroWin ? 1 : ((lastUpd >= 0) ? 2 : (anyDone ? 1 : 0));
    else       act = anyDone ? 1 : 0;

    if (c < 6) {
        float m = -3.0e38f;
        #pragma unroll
        for (int r = 0; r < 4; r++) {
            float4 q = *(const float4*)(g + (size_t)r*MG);
            if (act == 0) *(float4*)(go + (size_t)r*MG) = q;
            else if (act == 1) *(float4*)(go + (size_t)r*MG) = make_float4(0,0,0,0);
            m = fmaxf(m, fmaxf(fmaxf(q.x, q.y), fmaxf(q.z, q.w)));
        }
        ws[WS_CACHE + ((size_t)b*6 + c)*MLSQ + idx] = m;
        if (!inWin) {
            float v = m;
            for (int t = 0; t < TT; t++) {
                if (dones[b*TT+t]) v = 0.0f;
                out[(size_t)(b*TT+t)*CHMF*MLSQ + (6+c)*MLSQ + idx] = v;
            }
        }
    } else {
        if (act == 2) return;
        if (act == 1) {
            float4 z = make_float4(0,0,0,0);
            #pragma unroll
            for (int r = 0; r < 4; r++) *(float4*)(go + (size_t)r*MG) = z;
        } else {
            #pragma unroll
            for (int r = 0; r < 4; r++)
                *(float4*)(go + (size_t)r*MG) = *(const float4*)(g + (size_t)r*MG);
        }
    }
}

// ---- node 3: fused gs2∘gs1, 18 channels, 16x16 tiles with AABB block-skip ----
__global__ __launch_bounds__(256) void k_gs(const float* __restrict__ planes,
                                            const float* __restrict__ ws,
                                            float* __restrict__ I2)
{
    int bt = blockIdx.z;
    const float* ab = ws + WS_AABB + bt*4;
    int ilo = (int)ab[0], ihi = (int)ab[1], jlo = (int)ab[2], jhi = (int)ab[3];
    int r0 = blockIdx.y*16, q0 = blockIdx.x*16;
    // skip tiles with no pixel in [ilo-2,ihi+2]x[jlo-2,jhi+2] (updl reads stay inside)
    if (r0+15 < ilo-2 || r0 > ihi+2 || q0+15 < jlo-2 || q0 > jhi+2) return;

    int i = r0 + (threadIdx.x >> 4);
    int j = q0 + (threadIdx.x & 15);
    int idx = i*ML + j;
    const float* sc = ws + WS_SCAL + bt*8;
    float c = sc[0], s = sc[1], stx = sc[2], sty = sc[3];
    float* o = I2 + (size_t)bt*NPL*MLSQ + idx;
    const float* pl = planes + (size_t)bt*VRSQ*CPAD;

    int   soff[16];
    float sw[16];
    float wsum = 0.0f;
    {
        float xg = (float)j * (float)(2.0/239.0) - 1.0f + stx;
        float yg = (float)i * (float)(2.0/239.0) - 1.0f + sty;
        float x = (xg + 1.0f)*0.5f*239.0f;
        float y = (yg + 1.0f)*0.5f*239.0f;
        float x0 = floorf(x), y0 = floorf(y);
        #pragma unroll
        for (int dy = 0; dy < 2; dy++) {
            float yi = y0 + dy;
            bool vy = (yi >= 0.0f && yi <= 239.0f);
            float wy = 1.0f - fabsf(y - yi);
            #pragma unroll
            for (int dx = 0; dx < 2; dx++) {
                float xi = x0 + dx;
                bool vx = (xi >= 0.0f && xi <= 239.0f);
                float w2v = (vy && vx) ? (1.0f - fabsf(x - xi)) * wy : 0.0f;
                int ci = (dy*2 + dx)*4;
                float xg1 = (float)(int)xi * (float)(2.0/239.0) - 1.0f;
                float yg1 = (float)(int)yi * (float)(2.0/239.0) - 1.0f;
                float gxr = c*xg1 - s*yg1;
                float gyr = s*xg1 + c*yg1;
                float xx = (gxr + 1.0f)*0.5f*239.0f;
                float yy = (gyr + 1.0f)*0.5f*239.0f;
                float xx0 = floorf(xx), yy0 = floorf(yy);
                #pragma unroll
                for (int dy1 = 0; dy1 < 2; dy1++) {
                    float syi = yy0 + dy1;
                    bool v1y = (syi >= 120.0f && syi < 220.0f);
                    float wy1 = 1.0f - fabsf(yy - syi);
                    #pragma unroll
                    for (int dx1 = 0; dx1 < 2; dx1++) {
                        float sxi = xx0 + dx1;
                        bool v1 = v1y && (sxi >= 70.0f && sxi < 170.0f);
                        float w1v = v1 ? (1.0f - fabsf(xx - sxi)) * wy1 : 0.0f;
                        float wt = w2v * w1v;
                        soff[ci + dy1*2 + dx1] = v1 ? ((int)syi - 120)*VR + ((int)sxi - 70) : 0;
                        sw[ci + dy1*2 + dx1] = wt;
                        wsum += wt;
                    }
                }
            }
        }
    }

    if (wsum <= 0.0f) {
        #pragma unroll
        for (int cc = 0; cc < NPL; cc++) o[(size_t)cc*MLSQ] = 0.0f;
        return;
    }
    float acc[NPL];
    #pragma unroll
    for (int cc = 0; cc < NPL; cc++) acc[cc] = 0.0f;
    #pragma unroll
    for (int k = 0; k < 16; k++) {
        float w = sw[k];
        if (w == 0.0f) continue;
        const float* pb = pl + (size_t)soff[k]*CPAD;
        float4 a0 = *(const float4*)(pb + 0);
        float4 a1 = *(const float4*)(pb + 4);
        float4 a2 = *(const float4*)(pb + 8);
        float4 a3 = *(const float4*)(pb + 12);
        float2 a4 = *(const float2*)(pb + 16);
        acc[0]  += fminf(a0.x, 1.0f) * w;
        acc[1]  += fminf(a0.y, 1.0f) * w;
        acc[2]  += fminf(a0.z / 5.0f, 1.0f) * w;
        acc[3]  += fminf(a0.w / 5.0f, 1.0f) * w;
        acc[4]  += fminf(a1.x / 5.0f, 1.0f) * w;
        acc[5]  += fminf(a1.y / 5.0f, 1.0f) * w;
        acc[6]  += fminf(a1.z / 5.0f, 1.0f) * w;
        acc[7]  += fminf(a1.w / 5.0f, 1.0f) * w;
        acc[8]  += fminf(a2.x / 5.0f, 1.0f) * w;
        acc[9]  += fminf(a2.y / 5.0f, 1.0f) * w;
        acc[10] += fminf(a2.z / 5.0f, 1.0f) * w;
        acc[11] += fminf(a2.w / 5.0f, 1.0f) * w;
        acc[12] += fminf(a3.x / 5.0f, 1.0f) * w;
        acc[13] += fminf(a3.y / 5.0f, 1.0f) * w;
        acc[14] += fminf(a3.z / 5.0f, 1.0f) * w;
        acc[15] += fminf(a3.w / 5.0f, 1.0f) * w;
        acc[16] += fminf(a4.x / 5.0f, 1.0f) * w;
        acc[17] += fminf(a4.y / 5.0f, 1.0f) * w;
    }
    #pragma unroll
    for (int cc = 0; cc < NPL; cc++) o[(size_t)cc*MLSQ] = acc[cc];
}

// ---- node 4: channel-group temporal evolution; barrier-free, hoisted loads ----
// groups: 0={0(pool)}, 1={1,2,3}, 2={4,5}, 3..6 = sem quads
// wave layout: each wave = 4 rows x 16 cols -> gmax 4x4 cell lives in one wave
__global__ __launch_bounds__(256) void k_updl7(const float* __restrict__ I2,
                                               const float* __restrict__ ws,
                                               const float* __restrict__ ilm,
                                               const int* __restrict__ dones,
                                               const int* __restrict__ updg,
                                               const int* __restrict__ lmb,
                                               float* __restrict__ fl,
                                               float* __restrict__ fg,
                                               float* __restrict__ out)
{
    int bz = blockIdx.z;
    int b = bz / 7, g = bz % 7;
    int gi = blockIdx.y;                             // 0..59 (4-row group)
    int bx = blockIdx.x;                             // 0..3 col tile
    int wv = threadIdx.x >> 6, lane = threadIdx.x & 63;
    int jt = (bx < 3) ? bx*64 : 176;                 // tile 3 overlaps tile 2 (benign)
    int j0 = jt + wv*16;                             // this wave's 16-col strip
    int r  = lane >> 4, cc = lane & 15;
    int i = gi*4 + r;
    int j = j0 + cc;
    int idx = i*ML + j;

    int ncl, cl[4];
    switch (g) {
        case 0:  ncl = 1; cl[0] = 0; cl[1] = 0; cl[2] = 0; cl[3] = 0; break;
        case 1:  ncl = 3; cl[0] = 1; cl[1] = 2; cl[2] = 3; cl[3] = 0; break;
        case 2:  ncl = 2; cl[0] = 4; cl[1] = 5; cl[2] = 0; cl[3] = 0; break;
        default: ncl = 4; { int cc0 = 6 + (g-3)*4;
                 cl[0] = cc0; cl[1] = cc0+1; cl[2] = cc0+2; cl[3] = cc0+3; } break;
    }
    bool hasG = (g <= 2);

    const float* lmsrc = ilm + (size_t)b*CHL*MLSQ;
    float* lm = fl + (size_t)b*CHL*MLSQ;
    int y0 = lmb[b*4+0], x0 = lmb[b*4+2];            // %4==0 holds for this problem
    bool zeroWin = ws[WS_FLAGS + b*4 + 1] > 0.5f;
    int lastUpd = (int)ws[WS_FLAGS + b*4 + 2];

    float S[4];
    #pragma unroll
    for (int q = 0; q < 4; q++) {
        int c = cl[q];
        S[q] = (q < ncl && c != 2) ? lmsrc[c*MLSQ + idx] : 0.0f;
    }

    // gmax writer: one lane per 4x4 cell (r==0, cc%4==0)
    bool writer = hasG && (r == 0) && ((cc & 3) == 0);
    int cellY = (y0 >> 2) + gi;
    int cellX = (x0 >> 2) + (j0 >> 2) + (cc >> 2);
    float W[3];
    if (writer) {
        #pragma unroll
        for (int q = 0; q < 3; q++)
            if (q < ncl)
                W[q] = ws[WS_CACHE + ((size_t)b*6 + cl[q])*MLSQ + cellY*ML + cellX];
    }

    // ---- phase 1: hoisted, guarded gathers for all 4 timesteps ----
    float gv[TT][4];
    #pragma unroll
    for (int t = 0; t < TT; t++) {
        int bt = b*TT + t;
        const float* src = I2 + (size_t)bt*NPL*MLSQ;
        const float* ab = ws + WS_AABB + bt*4;
        int ilo = (int)ab[0], ihi = (int)ab[1], jlo = (int)ab[2], jhi = (int)ab[3];
        bool inA = (i >= ilo) && (i <= ihi) && (j >= jlo) && (j <= jhi);
        gv[t][0] = 0.0f; gv[t][1] = 0.0f; gv[t][2] = 0.0f; gv[t][3] = 0.0f;
        if (g == 0) {
            bool inP = (i >= ilo-1) && (i <= ihi+1) && (j >= jlo-1) && (j <= jhi+1);
            if (inP) {
                float m = -3.0e38f;
                for (int di = -1; di <= 1; di++) {
                    int ii = i + di; if (ii < 0 || ii >= ML) continue;
                    for (int dj = -1; dj <= 1; dj++) {
                        int jj = j + dj; if (jj < 0 || jj >= ML) continue;
                        m = fmaxf(m, src[ii*ML + jj]);
                    }
                }
                gv[t][0] = m;
            }
        } else if (g == 1) {
            if (inA) gv[t][0] = src[MLSQ + idx];
        } else if (g >= 3) {
            if (inA) {
                #pragma unroll
                for (int q = 0; q < 4; q++)
                    gv[t][q] = src[(size_t)(cl[q]-4)*MLSQ + idx];
            }
        }
    }

    // ---- phase 2: prefix evolution, outputs, in-wave gmax reduce ----
    #pragma unroll
    for (int t = 0; t < TT; t++) {
        int bt = b*TT + t;
        bool done = dones[bt] != 0;
        bool upd  = updg[bt] != 0;
        float* mf = out + (size_t)bt*CHMF*MLSQ;
        const float* sc = ws + WS_SCAL + bt*8;
        float acx = sc[4], acy = sc[5];
        float ddx = (float)j - acx, ddy = (float)i - acy;
        float d2 = ddx*ddx + ddy*ddy;
        float curr = (d2 <= 4.0f) ? 1.0f : 0.0f;
        float bc   = (d2 <= 1600.0f) ? 1.0f : 0.0f;

        size_t goff = (size_t)(y0+i)*MG + (x0+j);
        bool wrG = (t == lastUpd) && !zeroWin;

        #pragma unroll
        for (int q = 0; q < 4; q++) {
            if (q >= ncl) continue;
            int c = cl[q];
            if (done) S[q] = 0.0f;
            float nv;
            if      (c == 0) nv = fmaxf(S[q], gv[t][0]);
            else if (c == 1) nv = fmaxf(S[q], gv[t][0]);
            else if (c == 2) nv = curr;
            else if (c == 3) nv = fmaxf(S[q], curr);
            else if (c == 4) nv = fmaxf(S[q], bc);
            else if (c == 5) nv = S[q];
            else             nv = fmaxf(S[q], gv[t][q]);
            S[q] = nv;
            mf[(size_t)(c < 6 ? c : c + 6)*MLSQ + idx] = nv;
            if (wrG) fg[((size_t)b*CHL + c)*MGSQ + goff] = nv;
        }

        if (hasG) {
            #pragma unroll
            for (int q = 0; q < 3; q++) {
                if (q >= ncl) continue;
                float v = S[q];
                v = fmaxf(v, __shfl_xor(v, 1, 64));    // cols within 4-group
                v = fmaxf(v, __shfl_xor(v, 2, 64));
                v = fmaxf(v, __shfl_xor(v, 16, 64));   // rows
                v = fmaxf(v, __shfl_xor(v, 32, 64));
                if (writer) {
                    if (done) W[q] = 0.0f;
                    if (upd)  W[q] = v;
                    mf[(size_t)(6 + cl[q])*MLSQ + cellY*ML + cellX] = W[q];
                }
            }
        }
    }
    #pragma unroll
    for (int q = 0; q < 4; q++)
        if (q < ncl) lm[(size_t)cl[q]*MLSQ + idx] = S[q];
}

extern "C" void kernel_launch(void* const* d_in, const int* in_sizes, int n_in,
                              void* d_out, int out_size, void* d_ws, size_t ws_size,
                              hipStream_t stream)
{
    const float* obs   = (const float*)d_in[0];
    const float* pd    = (const float*)d_in[1];
    const float* cam   = (const float*)d_in[2];
    const float* ilm   = (const float*)d_in[3];
    const float* igm   = (const float*)d_in[4];
    const float* ilp   = (const float*)d_in[5];
    const float* org   = (const float*)d_in[7];
    const int*   dones = (const int*)d_in[8];
    const int*   updg  = (const int*)d_in[9];
    const int*   lmb   = (const int*)d_in[10];
    float* out = (float*)d_out;
    float* ws  = (float*)d_ws;

    float* fl     = out + OFF_FL;
    float* fg     = out + OFF_FG;
    float* planes = ws + WS_PLANES;
    float* I2v    = ws + WS_I2;

    k_stage1<<<1 + 75*BB*TT, 256, 0, stream>>>(obs, cam, pd, ilp, org, lmb,
                                               dones, updg, out, ws);
    k_stage2<<<NSPLAT + 225*CHL*BB, 256, 0, stream>>>(igm, dones, lmb,
                                                      planes, fg, out, ws);
    k_gs<<<dim3(15, 15, BB*TT), 256, 0, stream>>>(planes, ws, I2v);
    k_updl7<<<dim3(4, 60, BB*7), 256, 0, stream>>>(I2v, ws, ilm, dones, updg, lmb,
                                                   fl, fg, out);
}